// Round 12
// baseline (729.580 us; speedup 1.0000x reference)
//
#include <hip/hip_runtime.h>

typedef unsigned short u16;
typedef __attribute__((ext_vector_type(8))) short short8;
typedef __attribute__((ext_vector_type(4))) float f32x4;

#define BATCH 256
#define S_LEN 100
#define EMB   1024
#define NHEAD 16
#define HDIM  64

__device__ __forceinline__ float b2f(u16 h) {
  union { unsigned u; float f; } v; v.u = ((unsigned)h) << 16; return v.f;
}
__device__ __forceinline__ u16 f2bf(float f) {
  union { float f; unsigned u; } v; v.f = f;
  unsigned r = v.u + 0x7fffu + ((v.u >> 16) & 1u);
  return (u16)(r >> 16);
}

__device__ __forceinline__ void gld_lds16(const u16* g, u16* l) {
  __builtin_amdgcn_global_load_lds((const __attribute__((address_space(1))) void*)g,
                                   (__attribute__((address_space(3))) void*)l,
                                   16, 0, 0);
}

#define MFMA16(a, b, c) __builtin_amdgcn_mfma_f32_16x16x32_bf16(a, b, c, 0, 0, 0)

// ---------------------------------------------------------------------------
// Weight transpose+cast: W[k][n] (1024x1024 f32) -> Wt[n][k] bf16. grid(16,16,4)
// ---------------------------------------------------------------------------
__global__ __launch_bounds__(256) void w_xpose(
    const float* __restrict__ Wq, const float* __restrict__ Wk,
    const float* __restrict__ Wv, const float* __restrict__ Wo,
    u16* __restrict__ WtQ, u16* __restrict__ WtK,
    u16* __restrict__ WtV, u16* __restrict__ WtO)
{
  __shared__ u16 tile[64 * 73];
  int z = blockIdx.z;
  const float* W = (z == 0) ? Wq : (z == 1) ? Wk : (z == 2) ? Wv : Wo;
  u16* Wt        = (z == 0) ? WtQ : (z == 1) ? WtK : (z == 2) ? WtV : WtO;
  int k0 = blockIdx.x * 64, n0 = blockIdx.y * 64;
  for (int idx = threadIdx.x; idx < 4096; idx += 256) {
    int r = idx >> 6, c = idx & 63;
    tile[r * 73 + c] = f2bf(W[(size_t)(k0 + r) * EMB + n0 + c]);
  }
  __syncthreads();
  for (int idx = threadIdx.x; idx < 4096; idx += 256) {
    int c = idx >> 6, r = idx & 63;
    Wt[(size_t)(n0 + c) * EMB + k0 + r] = tile[r * 73 + c];
  }
}

// ---------------------------------------------------------------------------
// x [B][E][S] f32 -> xT [B][S][E] bf16, adding pos_encoding[s][e]. grid(16,B)
// ---------------------------------------------------------------------------
__global__ __launch_bounds__(256) void xpose_pos(
    const float* __restrict__ x, const float* __restrict__ pos, u16* __restrict__ xT)
{
  __shared__ float tile[64 * 105];
  int e0 = blockIdx.x * 64;
  int b  = blockIdx.y;
  const float* xb = x + (size_t)b * EMB * S_LEN;
  for (int idx = threadIdx.x; idx < 6400; idx += 256) {
    int i = idx / 100, s = idx - i * 100;
    tile[i * 105 + s] = xb[(size_t)(e0 + i) * S_LEN + s];
  }
  __syncthreads();
  for (int idx = threadIdx.x; idx < 6400; idx += 256) {
    int s = idx >> 6, i = idx & 63;
    float v = tile[i * 105 + s] + pos[(size_t)s * EMB + e0 + i];
    xT[(size_t)b * (S_LEN * EMB) + (size_t)s * EMB + e0 + i] = f2bf(v);
  }
}

// ---------------------------------------------------------------------------
// tmp [B][S][E] bf16 -> out [B][E][S] f32.  grid (16, B)
// out is a pure output (never re-read on device) -> nontemporal stores.
// ---------------------------------------------------------------------------
__global__ __launch_bounds__(256) void out_xpose(
    const u16* __restrict__ tmp, float* __restrict__ out)
{
  __shared__ u16 tile[100 * 73];
  int e0 = blockIdx.x * 64;
  int b  = blockIdx.y;
  for (int idx = threadIdx.x; idx < 6400; idx += 256) {
    int s = idx >> 6, i = idx & 63;
    tile[s * 73 + i] = tmp[(size_t)b * (S_LEN * EMB) + (size_t)s * EMB + e0 + i];
  }
  __syncthreads();
  for (int idx = threadIdx.x; idx < 6400; idx += 256) {
    int i = idx / 100, s = idx - i * 100;
    __builtin_nontemporal_store(b2f(tile[s * 73 + i]),
                                &out[((size_t)b * EMB + e0 + i) * S_LEN + s]);
  }
}

// ---------------------------------------------------------------------------
// GEMM 256x256 tile, 8-phase pipelined, counted vmcnt gates, setprio,
// XOR-swizzled LDS. Body = exact R4 kernel (measured 207-209 us, VGPR 100).
//
// Round-12 change: GRID ORDER ONLY. grid is now (Nblk=4, Mblk=100, z):
// consecutive linear block ids share the same A panel (same m0) and dispatch
// concurrently across XCDs -> A panel fetched to L3 once, siblings hit L3
// instead of HBM. FETCH_SIZE predicted 284 -> ~150 MB; gate latency drops.
// ---------------------------------------------------------------------------
__global__ __launch_bounds__(512) void gemm256(
    const u16* __restrict__ A,
    const u16* __restrict__ Bt0, const u16* __restrict__ Bt1, const u16* __restrict__ Bt2,
    const float* __restrict__ bias0, const float* __restrict__ bias1, const float* __restrict__ bias2,
    u16* __restrict__ C0, u16* __restrict__ C1, u16* __restrict__ C2)
{
  __shared__ u16 lds[2][2][16384];   // [buf][0=A,1=B][256 rows * 64]

  const int z = blockIdx.z;
  const u16* Bt     = (z == 0) ? Bt0 : (z == 1) ? Bt1 : Bt2;
  const float* bias = (z == 0) ? bias0 : (z == 1) ? bias1 : bias2;
  u16* C            = (z == 0) ? C0 : (z == 1) ? C1 : C2;

  const int tid  = threadIdx.x;
  const int wave = tid >> 6, lane = tid & 63;
  const int quad = lane >> 4, l16 = lane & 15;
  const int m0 = blockIdx.y * 256, n0 = blockIdx.x * 256;   // swapped mapping
  const int WM = (wave >> 2) * 128, WN = (wave & 3) * 64;

  // staging address constants (pre-swizzled global source, linear LDS dest)
  const int rq8  = tid >> 3;                         // 0..63
  const int jg   = ((tid & 7) ^ (rq8 & 7)) << 3;     // swizzled chunk col
  const int hi96 = (tid >= 256) ? 96 : 0;
  const int aw   = (wave & 3) * 8 + (wave >> 2) * 128; // A dest wave row base
  const size_t aBase = (size_t)(m0 + rq8 + hi96) * EMB + jg;
  const size_t bBase = (size_t)(n0 + rq8) * EMB + jg;

#define STB(nb, u, k1) gld_lds16(Bt + bBase + (size_t)((u) * 64) * EMB + (k1), \
                                 &lds[nb][1][(u) * 4096 + wave * 512])
#define STA(nb, p, k1) gld_lds16(A + aBase + (size_t)((p) * 32) * EMB + (k1), \
                                 &lds[nb][0][((p) * 32 + aw) * 64])
#define GATE(N) { asm volatile("s_waitcnt vmcnt(" #N ")" ::: "memory"); \
                  __builtin_amdgcn_s_barrier(); }

  f32x4 acc[8][4] = {};

  // prologue: tile 0 -> buf 0 (issue in consumption order), gate u0..u4
  STB(0, 0, 0); STB(0, 1, 0); STB(0, 2, 0); STB(0, 3, 0);
  STA(0, 0, 0); STA(0, 1, 0); STA(0, 2, 0); STA(0, 3, 0);
  GATE(3);

  const int swz = l16 & 7;
  const int cA  = (quad ^ swz) << 3;        // kk=0 chunk (u16 offset)
  const int cB  = ((quad + 4) ^ swz) << 3;  // kk=32 chunk

#define PH(q, STAGES, GATE_) { \
    short8 aF[2][2]; \
    aF[0][0] = *(const short8*)(a0 + (2 * (q)) * 1024); \
    aF[0][1] = *(const short8*)(a1 + (2 * (q)) * 1024); \
    aF[1][0] = *(const short8*)(a0 + (2 * (q) + 1) * 1024); \
    aF[1][1] = *(const short8*)(a1 + (2 * (q) + 1) * 1024); \
    STAGES; \
    __builtin_amdgcn_s_setprio(1); \
    _Pragma("unroll") \
    for (int kh = 0; kh < 2; ++kh) { \
      _Pragma("unroll") \
      for (int ni = 0; ni < 4; ++ni) { \
        acc[2 * (q)][ni]     = MFMA16(aF[0][kh], bF[kh][ni], acc[2 * (q)][ni]); \
        acc[2 * (q) + 1][ni] = MFMA16(aF[1][kh], bF[kh][ni], acc[2 * (q) + 1][ni]); \
      } \
    } \
    __builtin_amdgcn_s_setprio(0); \
    GATE_; \
  }

  for (int t = 0; t < 16; ++t) {
    const int cb = t & 1, nb = cb ^ 1;
    const u16* lA_ = lds[cb][0];
    const u16* lB_ = lds[cb][1];
    const u16* a0 = lA_ + (WM + l16) * 64 + cA;
    const u16* a1 = lA_ + (WM + l16) * 64 + cB;
    const u16* b0 = lB_ + (WN + l16) * 64 + cA;
    const u16* b1 = lB_ + (WN + l16) * 64 + cB;
    const int k1 = (t + 1) << 6;

    // B fragments: load ONCE per tile, live in VGPRs across all 4 phases.
    short8 bF[2][4];
#pragma unroll
    for (int ni = 0; ni < 4; ++ni) {
      bF[0][ni] = *(const short8*)(b0 + ni * 1024);
      bF[1][ni] = *(const short8*)(b1 + ni * 1024);
    }

    if (t < 15) {
      PH(0, { STB(nb, 0, k1); STB(nb, 1, k1); }, GATE(4));
      PH(1, { STB(nb, 2, k1); STB(nb, 3, k1); }, GATE(5));
      PH(2, { STA(nb, 0, k1); STA(nb, 1, k1); }, GATE(6));
      PH(3, { STA(nb, 2, k1); STA(nb, 3, k1); }, GATE(3));
    } else {
      PH(0, { (void)0; }, GATE(2));
      PH(1, { (void)0; }, GATE(1));
      PH(2, { (void)0; }, GATE(0));
      PH(3, { (void)0; }, { (void)0; });
    }
  }

#pragma unroll
  for (int ni = 0; ni < 4; ++ni) {
    int col = n0 + WN + ni * 16 + l16;
    float bv = bias[col];
#pragma unroll
    for (int mi = 0; mi < 8; ++mi) {
#pragma unroll
      for (int r = 0; r < 4; ++r) {
        int row = m0 + WM + mi * 16 + quad * 4 + r;
        C[(size_t)row * EMB + col] = f2bf(acc[mi][ni][r] + bv);
      }
    }
  }
#undef PH
#undef STB
#undef STA
#undef GATE
}

// ---------------------------------------------------------------------------
// Attention: one block per (b,h).  LDS 71.7 KB -> 2 blocks/CU.
// attn_out (pure output) written nontemporal.
// ---------------------------------------------------------------------------
__global__ __launch_bounds__(256) void attn_kernel(
    const u16* __restrict__ Q, const u16* __restrict__ Kb, const u16* __restrict__ V,
    float* __restrict__ attn_out, u16* __restrict__ attended)
{
  __shared__ u16 sQK[112 * 64 * 2];
  __shared__ __align__(16) char smemB[100 * 105 * 4];
  __shared__ float sRed[256];

  u16* sQ   = sQK;
  u16* sK   = sQK + 112 * 64;
  u16* sP   = sQK;                    // overlays q+k after softmax
  float* sS = (float*)smemB;          // scores, stride 105
  u16* sVt  = (u16*)smemB;            // overlays sS after attn_out written

  const int bh = blockIdx.x;
  const int b = bh >> 4, h = bh & 15;
  const int tid = threadIdx.x;
  const int wave = tid >> 6, lane = tid & 63;
  const int quad = lane >> 4, l16 = lane & 15;
  const size_t qbase = (size_t)b * S_LEN * EMB + h * HDIM;

  // ---- preload V into registers (800 16B chunks) ----
  uint4 vr0, vr1, vr2, vr3 = make_uint4(0, 0, 0, 0);
  {
    int c0 = tid, c1 = tid + 256, c2 = tid + 512;
    vr0 = *(const uint4*)(V + qbase + (size_t)(c0 >> 3) * EMB + ((c0 & 7) << 3));
    vr1 = *(const uint4*)(V + qbase + (size_t)(c1 >> 3) * EMB + ((c1 & 7) << 3));
    vr2 = *(const uint4*)(V + qbase + (size_t)(c2 >> 3) * EMB + ((c2 & 7) << 3));
    if (tid < 32) {
      int c3 = tid + 768;
      vr3 = *(const uint4*)(V + qbase + (size_t)(c3 >> 3) * EMB + ((c3 & 7) << 3));
    }
  }

  // ---- stage q, k swizzled; zero pad rows 100..111 ----
  for (int c = tid; c < 896; c += 256) {
    int s = c >> 3, j = c & 7;
    int jg = (j ^ (s & 7)) << 3;
    uint4 qv = make_uint4(0, 0, 0, 0), kv = make_uint4(0, 0, 0, 0);
    if (s < S_LEN) {
      qv = *(const uint4*)(Q  + qbase + (size_t)s * EMB + jg);
      kv = *(const uint4*)(Kb + qbase + (size_t)s * EMB + jg);
    }
    *(uint4*)(sQ + c * 8) = qv;
    *(uint4*)(sK + c * 8) = kv;
  }
  __syncthreads();

  // ---- QK^T: 7x7 16x16 tiles, K=64, swizzled frag reads ----
  for (int t = wave; t < 49; t += 4) {
    int mi = t / 7, ni = t - mi * 7;
    f32x4 acc = {0.f, 0.f, 0.f, 0.f};
#pragma unroll
    for (int kk = 0; kk < 64; kk += 32) {
      int rq = mi * 16 + l16, rk = ni * 16 + l16;
      int cix = (kk >> 3) + quad;
      short8 a  = *(const short8*)(sQ + rq * 64 + ((cix ^ (rq & 7)) << 3));
      short8 bb = *(const short8*)(sK + rk * 64 + ((cix ^ (rk & 7)) << 3));
      acc = __builtin_amdgcn_mfma_f32_16x16x32_bf16(a, bb, acc, 0, 0, 0);
    }
    int col = ni * 16 + l16;
#pragma unroll
    for (int r = 0; r < 4; ++r) {
      int row = mi * 16 + quad * 4 + r;
      if (row < S_LEN && col < S_LEN) sS[row * 105 + col] = acc[r] * 0.125f;
    }
  }
  __syncthreads();

  // ---- zero P pad rows 100..111 (all threads) ----
  for (int i = tid; i < 192; i += 256)
    *(uint4*)(sP + (100 + (i >> 4)) * 128 + ((i & 15) << 3)) = make_uint4(0, 0, 0, 0);

  // ---- softmax: TWO threads per row; split accumulator chains ----
  if (tid < 200) {
    int row = tid >> 1, half = tid & 1;
    float* Srow = sS + row * 105;
    int c0 = half * 50, c1 = c0 + 50;
    float m0 = -1e30f, m1 = -1e30f;
    for (int c = c0; c < c1; c += 2) {
      m0 = fmaxf(m0, Srow[c]);
      m1 = fmaxf(m1, Srow[c + 1]);
    }
    sRed[tid] = fmaxf(m0, m1);
  }
  __syncthreads();
  if (tid < 200) {
    int row = tid >> 1, half = tid & 1;
    float* Srow = sS + row * 105;
    float mxv = fmaxf(sRed[row * 2], sRed[row * 2 + 1]);
    int c0 = half * 50, c1 = c0 + 50;
    float s0 = 0.f, s1 = 0.f;
    for (int c = c0; c < c1; c += 2) {
      float e0 = __expf(Srow[c] - mxv);
      float e1 = __expf(Srow[c + 1] - mxv);
      Srow[c] = e0; Srow[c + 1] = e1;
      s0 += e0; s1 += e1;
    }
    sRed[tid] = s0 + s1;
  }
  __syncthreads();
  if (tid < 200) {
    int row = tid >> 1, half = tid & 1;
    float* Srow = sS + row * 105;
    u16* Prow = sP + row * 128;
    int rs = row & 7;
    float inv = 1.f / (sRed[row * 2] + sRed[row * 2 + 1]);
    int c0 = half * 50, c1 = c0 + 50;
    for (int c = c0; c < c1; ++c) {
      float p = Srow[c] * inv;
      Srow[c] = p;
      Prow[(((c >> 3) ^ rs) << 3) + (c & 7)] = f2bf(p);
    }
    if (half == 1) {
      for (int c = S_LEN; c < 128; ++c)
        Prow[(((c >> 3) ^ rs) << 3) + (c & 7)] = 0;
    }
  }
  __syncthreads();

  // ---- coalesced attn_out write from sS (nontemporal: pure output) ----
  {
    float* ao = attn_out + (size_t)bh * (S_LEN * S_LEN);
    for (int i = tid; i < S_LEN * S_LEN; i += 256) {
      int r = i / 100, c = i - r * 100;
      __builtin_nontemporal_store(sS[r * 105 + c], &ao[i]);
    }
  }
  __syncthreads();

  // ---- build V^T over the score buffer: zero, then scatter from regs ----
  for (int i = tid; i < 1024; i += 256)
    *(uint4*)(sVt + i * 8) = make_uint4(0, 0, 0, 0);
  __syncthreads();
  {
    const u16* p0 = (const u16*)&vr0;
    const u16* p1 = (const u16*)&vr1;
    const u16* p2 = (const u16*)&vr2;
    const u16* p3 = (const u16*)&vr3;
    int c0 = tid, c1 = tid + 256, c2 = tid + 512, c3 = tid + 768;
#pragma unroll
    for (int j = 0; j < 8; ++j) {
      int s, d;
      s = c0 >> 3; d = ((c0 & 7) << 3) + j;
      sVt[d * 128 + (((s >> 3) ^ (d & 7)) << 3) + (s & 7)] = p0[j];
      s = c1 >> 3; d = ((c1 & 7) << 3) + j;
      sVt[d * 128 + (((s >> 3) ^ (d & 7)) << 3) + (s & 7)] = p1[j];
      s = c2 >> 3; d = ((c2 & 7) << 3) + j;
      sVt[d * 128 + (((s >> 3) ^ (d & 7)) << 3) + (s & 7)] = p2[j];
      if (tid < 32) {
        s = c3 >> 3; d = ((c3 & 7) << 3) + j;
        sVt[d * 128 + (((s >> 3) ^ (d & 7)) << 3) + (s & 7)] = p3[j];
      }
    }
  }
  __syncthreads();

  // ---- PV: 7x4 16x16 tiles, K=128 (cols >=100 zero), swizzled frag reads ----
  for (int t = wave; t < 28; t += 4) {
    int mi = t >> 2, ni = t & 3;
    f32x4 acc = {0.f, 0.f, 0.f, 0.f};
#pragma unroll
    for (int kk = 0; kk < 128; kk += 32) {
      int rp = mi * 16 + l16, rv = ni * 16 + l16;
      int cix = (kk >> 3) + quad;
      short8 a  = *(const short8*)(sP  + rp * 128 + ((cix ^ (rp & 7)) << 3));
      short8 bb = *(const short8*)(sVt + rv * 128 + ((cix ^ (rv & 7)) << 3));
      acc = __builtin_amdgcn_mfma_f32_16x16x32_bf16(a, bb, acc, 0, 0, 0);
    }
    int col = ni * 16 + l16;
#pragma unroll
    for (int r = 0; r < 4; ++r) {
      int row = mi * 16 + quad * 4 + r;
      if (row < S_LEN)
        attended[((size_t)b * S_LEN + row) * EMB + h * HDIM + col] = f2bf(acc[r]);
    }
  }
}

// ---------------------------------------------------------------------------
extern "C" void kernel_launch(void* const* d_in, const int* in_sizes, int n_in,
                              void* d_out, int out_size, void* d_ws, size_t ws_size,
                              hipStream_t stream) {
  const float* x   = (const float*)d_in[0];
  const float* Wq  = (const float*)d_in[1];
  const float* bq  = (const float*)d_in[2];
  const float* Wk  = (const float*)d_in[3];
  const float* bk  = (const float*)d_in[4];
  const float* Wv  = (const float*)d_in[5];
  const float* bv  = (const float*)d_in[6];
  const float* Wo  = (const float*)d_in[7];
  const float* bo  = (const float*)d_in[8];
  const float* pos = (const float*)d_in[9];

  float* out  = (float*)d_out;                     // [B][E][S] f32
  float* attn = out + (size_t)BATCH * EMB * S_LEN; // [B][H][S][S] f32

  const size_t MTOT = (size_t)BATCH * S_LEN;       // 25600
  u16* ws   = (u16*)d_ws;
  u16* xT   = ws;                                  // [25600][1024] bf16
  u16* Qb   = ws + MTOT * EMB;
  u16* Kbuf = ws + 2 * MTOT * EMB;
  u16* Vb   = ws + 3 * MTOT * EMB;
  u16* WtQ  = ws + 4 * MTOT * EMB;
  u16* WtK  = WtQ + (size_t)EMB * EMB;
  u16* WtV  = WtK + (size_t)EMB * EMB;
  u16* WtO  = WtV + (size_t)EMB * EMB;
  u16* attended = xT;                              // reuse (xT dead after QKV gemm)
  u16* tmp      = Qb;                              // reuse (Q dead after attention)

  w_xpose<<<dim3(16, 16, 4), 256, 0, stream>>>(Wq, Wk, Wv, Wo, WtQ, WtK, WtV, WtO);
  xpose_pos<<<dim3(16, BATCH), 256, 0, stream>>>(x, pos, xT);
  gemm256<<<dim3(4, 100, 3), 512, 0, stream>>>(xT, WtQ, WtK, WtV, bq, bk, bv,
                                               Qb, Kbuf, Vb);
  attn_kernel<<<dim3(BATCH * NHEAD), 256, 0, stream>>>(Qb, Kbuf, Vb, attn, attended);
  gemm256<<<dim3(4, 100, 1), 512, 0, stream>>>(attended, WtO, WtO, WtO, bo, bo, bo,
                                               tmp, tmp, tmp);
  out_xpose<<<dim3(16, BATCH), 256, 0, stream>>>(tmp, out);
}

// Round 14
// 704.583 us; speedup vs baseline: 1.0355x; 1.0355x over previous
//
#include <hip/hip_runtime.h>

typedef unsigned short u16;
typedef __attribute__((ext_vector_type(8))) short short8;
typedef __attribute__((ext_vector_type(4))) float f32x4;

#define BATCH 256
#define S_LEN 100
#define EMB   1024
#define NHEAD 16
#define HDIM  64

__device__ __forceinline__ float b2f(u16 h) {
  union { unsigned u; float f; } v; v.u = ((unsigned)h) << 16; return v.f;
}
__device__ __forceinline__ u16 f2bf(float f) {
  union { float f; unsigned u; } v; v.f = f;
  unsigned r = v.u + 0x7fffu + ((v.u >> 16) & 1u);
  return (u16)(r >> 16);
}

__device__ __forceinline__ void gld_lds16(const u16* g, u16* l) {
  __builtin_amdgcn_global_load_lds((const __attribute__((address_space(1))) void*)g,
                                   (__attribute__((address_space(3))) void*)l,
                                   16, 0, 0);
}

#define MFMA16(a, b, c) __builtin_amdgcn_mfma_f32_16x16x32_bf16(a, b, c, 0, 0, 0)

// ---------------------------------------------------------------------------
// Weight transpose+cast: W[k][n] (1024x1024 f32) -> Wt[n][k] bf16. grid(16,16,4)
// ---------------------------------------------------------------------------
__global__ __launch_bounds__(256) void w_xpose(
    const float* __restrict__ Wq, const float* __restrict__ Wk,
    const float* __restrict__ Wv, const float* __restrict__ Wo,
    u16* __restrict__ WtQ, u16* __restrict__ WtK,
    u16* __restrict__ WtV, u16* __restrict__ WtO)
{
  __shared__ u16 tile[64 * 73];
  int z = blockIdx.z;
  const float* W = (z == 0) ? Wq : (z == 1) ? Wk : (z == 2) ? Wv : Wo;
  u16* Wt        = (z == 0) ? WtQ : (z == 1) ? WtK : (z == 2) ? WtV : WtO;
  int k0 = blockIdx.x * 64, n0 = blockIdx.y * 64;
  for (int idx = threadIdx.x; idx < 4096; idx += 256) {
    int r = idx >> 6, c = idx & 63;
    tile[r * 73 + c] = f2bf(W[(size_t)(k0 + r) * EMB + n0 + c]);
  }
  __syncthreads();
  for (int idx = threadIdx.x; idx < 4096; idx += 256) {
    int c = idx >> 6, r = idx & 63;
    Wt[(size_t)(n0 + c) * EMB + k0 + r] = tile[r * 73 + c];
  }
}

// ---------------------------------------------------------------------------
// x [B][E][S] f32 -> xT [B][S][E] bf16, adding pos_encoding[s][e]. grid(16,B)
// ---------------------------------------------------------------------------
__global__ __launch_bounds__(256) void xpose_pos(
    const float* __restrict__ x, const float* __restrict__ pos, u16* __restrict__ xT)
{
  __shared__ float tile[64 * 105];
  int e0 = blockIdx.x * 64;
  int b  = blockIdx.y;
  const float* xb = x + (size_t)b * EMB * S_LEN;
  for (int idx = threadIdx.x; idx < 6400; idx += 256) {
    int i = idx / 100, s = idx - i * 100;
    tile[i * 105 + s] = xb[(size_t)(e0 + i) * S_LEN + s];
  }
  __syncthreads();
  for (int idx = threadIdx.x; idx < 6400; idx += 256) {
    int s = idx >> 6, i = idx & 63;
    float v = tile[i * 105 + s] + pos[(size_t)s * EMB + e0 + i];
    xT[(size_t)b * (S_LEN * EMB) + (size_t)s * EMB + e0 + i] = f2bf(v);
  }
}

// ---------------------------------------------------------------------------
// tmp [B][S][E] bf16 -> out [B][E][S] f32.  grid (16, B). nontemporal out.
// ---------------------------------------------------------------------------
__global__ __launch_bounds__(256) void out_xpose(
    const u16* __restrict__ tmp, float* __restrict__ out)
{
  __shared__ u16 tile[100 * 73];
  int e0 = blockIdx.x * 64;
  int b  = blockIdx.y;
  for (int idx = threadIdx.x; idx < 6400; idx += 256) {
    int s = idx >> 6, i = idx & 63;
    tile[s * 73 + i] = tmp[(size_t)b * (S_LEN * EMB) + (size_t)s * EMB + e0 + i];
  }
  __syncthreads();
  for (int idx = threadIdx.x; idx < 6400; idx += 256) {
    int i = idx / 100, s = idx - i * 100;
    __builtin_nontemporal_store(b2f(tile[s * 73 + i]),
                                &out[((size_t)b * EMB + e0 + i) * S_LEN + s]);
  }
}

// ---------------------------------------------------------------------------
// GEMM 256x256 tile, 8-phase pipelined, counted vmcnt gates, setprio,
// XOR-swizzled LDS. EXACT R11 config (measured best: 206-209 us, VGPR 100).
// Grid (100,4,z), m0 = blockIdx.x (R12's swap regressed: FETCH 284->322).
// ---------------------------------------------------------------------------
__global__ __launch_bounds__(512) void gemm256(
    const u16* __restrict__ A,
    const u16* __restrict__ Bt0, const u16* __restrict__ Bt1, const u16* __restrict__ Bt2,
    const float* __restrict__ bias0, const float* __restrict__ bias1, const float* __restrict__ bias2,
    u16* __restrict__ C0, u16* __restrict__ C1, u16* __restrict__ C2)
{
  __shared__ u16 lds[2][2][16384];   // [buf][0=A,1=B][256 rows * 64]

  const int z = blockIdx.z;
  const u16* Bt     = (z == 0) ? Bt0 : (z == 1) ? Bt1 : Bt2;
  const float* bias = (z == 0) ? bias0 : (z == 1) ? bias1 : bias2;
  u16* C            = (z == 0) ? C0 : (z == 1) ? C1 : C2;

  const int tid  = threadIdx.x;
  const int wave = tid >> 6, lane = tid & 63;
  const int quad = lane >> 4, l16 = lane & 15;
  const int m0 = blockIdx.x * 256, n0 = blockIdx.y * 256;
  const int WM = (wave >> 2) * 128, WN = (wave & 3) * 64;

  const int rq8  = tid >> 3;                         // 0..63
  const int jg   = ((tid & 7) ^ (rq8 & 7)) << 3;     // swizzled chunk col
  const int hi96 = (tid >= 256) ? 96 : 0;
  const int aw   = (wave & 3) * 8 + (wave >> 2) * 128;
  const size_t aBase = (size_t)(m0 + rq8 + hi96) * EMB + jg;
  const size_t bBase = (size_t)(n0 + rq8) * EMB + jg;

#define STB(nb, u, k1) gld_lds16(Bt + bBase + (size_t)((u) * 64) * EMB + (k1), \
                                 &lds[nb][1][(u) * 4096 + wave * 512])
#define STA(nb, p, k1) gld_lds16(A + aBase + (size_t)((p) * 32) * EMB + (k1), \
                                 &lds[nb][0][((p) * 32 + aw) * 64])
#define GATE(N) { asm volatile("s_waitcnt vmcnt(" #N ")" ::: "memory"); \
                  __builtin_amdgcn_s_barrier(); }

  f32x4 acc[8][4] = {};

  STB(0, 0, 0); STB(0, 1, 0); STB(0, 2, 0); STB(0, 3, 0);
  STA(0, 0, 0); STA(0, 1, 0); STA(0, 2, 0); STA(0, 3, 0);
  GATE(3);

  const int swz = l16 & 7;
  const int cA  = (quad ^ swz) << 3;
  const int cB  = ((quad + 4) ^ swz) << 3;

#define PH(q, STAGES, GATE_) { \
    short8 aF[2][2]; \
    aF[0][0] = *(const short8*)(a0 + (2 * (q)) * 1024); \
    aF[0][1] = *(const short8*)(a1 + (2 * (q)) * 1024); \
    aF[1][0] = *(const short8*)(a0 + (2 * (q) + 1) * 1024); \
    aF[1][1] = *(const short8*)(a1 + (2 * (q) + 1) * 1024); \
    STAGES; \
    __builtin_amdgcn_s_setprio(1); \
    _Pragma("unroll") \
    for (int kh = 0; kh < 2; ++kh) { \
      _Pragma("unroll") \
      for (int ni = 0; ni < 4; ++ni) { \
        acc[2 * (q)][ni]     = MFMA16(aF[0][kh], bF[kh][ni], acc[2 * (q)][ni]); \
        acc[2 * (q) + 1][ni] = MFMA16(aF[1][kh], bF[kh][ni], acc[2 * (q) + 1][ni]); \
      } \
    } \
    __builtin_amdgcn_s_setprio(0); \
    GATE_; \
  }

  for (int t = 0; t < 16; ++t) {
    const int cb = t & 1, nb = cb ^ 1;
    const u16* lA_ = lds[cb][0];
    const u16* lB_ = lds[cb][1];
    const u16* a0 = lA_ + (WM + l16) * 64 + cA;
    const u16* a1 = lA_ + (WM + l16) * 64 + cB;
    const u16* b0 = lB_ + (WN + l16) * 64 + cA;
    const u16* b1 = lB_ + (WN + l16) * 64 + cB;
    const int k1 = (t + 1) << 6;

    short8 bF[2][4];
#pragma unroll
    for (int ni = 0; ni < 4; ++ni) {
      bF[0][ni] = *(const short8*)(b0 + ni * 1024);
      bF[1][ni] = *(const short8*)(b1 + ni * 1024);
    }

    if (t < 15) {
      PH(0, { STB(nb, 0, k1); STB(nb, 1, k1); }, GATE(4));
      PH(1, { STB(nb, 2, k1); STB(nb, 3, k1); }, GATE(5));
      PH(2, { STA(nb, 0, k1); STA(nb, 1, k1); }, GATE(6));
      PH(3, { STA(nb, 2, k1); STA(nb, 3, k1); }, GATE(3));
    } else {
      PH(0, { (void)0; }, GATE(2));
      PH(1, { (void)0; }, GATE(1));
      PH(2, { (void)0; }, GATE(0));
      PH(3, { (void)0; }, { (void)0; });
    }
  }

#pragma unroll
  for (int ni = 0; ni < 4; ++ni) {
    int col = n0 + WN + ni * 16 + l16;
    float bv = bias[col];
#pragma unroll
    for (int mi = 0; mi < 8; ++mi) {
#pragma unroll
      for (int r = 0; r < 4; ++r) {
        int row = m0 + WM + mi * 16 + quad * 4 + r;
        C[(size_t)row * EMB + col] = f2bf(acc[mi][ni][r] + bv);
      }
    }
  }
#undef PH
#undef STB
#undef STA
#undef GATE
}

// ---------------------------------------------------------------------------
// Attention v3: swapped-QK^T register softmax (flash-style, S=100 D=64).
// One block (4 waves) per (b,h). LDS = V^T only (16.4 KB) -> ~4 blocks/CU.
// Layout re-audited round 13: regroup solves kt=2j+(quad>>1),
// quad'=2(quad&1)+(sI>>1), pair=sI&1; j=3 hi chunk (k>=112) zeroed;
// k in [100,112) zeroed by exp-mask. Vt build + B-frag reads verbatim from
// the twice-passed kernel.
// ---------------------------------------------------------------------------
__global__ __launch_bounds__(256) void attn_kernel(
    const u16* __restrict__ Q, const u16* __restrict__ Kb, const u16* __restrict__ V,
    float* __restrict__ attn_out, u16* __restrict__ attended)
{
  __shared__ u16 sVt[64 * 128];   // V^T [d][k], XOR-swizzled rows

  const int bh = blockIdx.x;
  const int b = bh >> 4, h = bh & 15;
  const int tid = threadIdx.x;
  const int wave = tid >> 6, lane = tid & 63;
  const int quad = lane >> 4, l16 = lane & 15;
  const size_t qbase = (size_t)b * S_LEN * EMB + h * HDIM;

  // ---- preload V into registers (800 16B chunks over 256 threads) ----
  uint4 vr0, vr1, vr2, vr3 = make_uint4(0, 0, 0, 0);
  {
    int c0 = tid, c1 = tid + 256, c2 = tid + 512;
    vr0 = *(const uint4*)(V + qbase + (size_t)(c0 >> 3) * EMB + ((c0 & 7) << 3));
    vr1 = *(const uint4*)(V + qbase + (size_t)(c1 >> 3) * EMB + ((c1 & 7) << 3));
    vr2 = *(const uint4*)(V + qbase + (size_t)(c2 >> 3) * EMB + ((c2 & 7) << 3));
    if (tid < 32) {
      int c3 = tid + 768;
      vr3 = *(const uint4*)(V + qbase + (size_t)(c3 >> 3) * EMB + ((c3 & 7) << 3));
    }
  }

  // ---- build V^T in LDS: zero, then scatter (verbatim-verified layout) ----
  for (int i = tid; i < 1024; i += 256)
    *(uint4*)(sVt + i * 8) = make_uint4(0, 0, 0, 0);
  __syncthreads();
  {
    const u16* p0 = (const u16*)&vr0;
    const u16* p1 = (const u16*)&vr1;
    const u16* p2 = (const u16*)&vr2;
    const u16* p3 = (const u16*)&vr3;
    int c0 = tid, c1 = tid + 256, c2 = tid + 512, c3 = tid + 768;
#pragma unroll
    for (int j = 0; j < 8; ++j) {
      int s, d;
      s = c0 >> 3; d = ((c0 & 7) << 3) + j;
      sVt[d * 128 + (((s >> 3) ^ (d & 7)) << 3) + (s & 7)] = p0[j];
      s = c1 >> 3; d = ((c1 & 7) << 3) + j;
      sVt[d * 128 + (((s >> 3) ^ (d & 7)) << 3) + (s & 7)] = p1[j];
      s = c2 >> 3; d = ((c2 & 7) << 3) + j;
      sVt[d * 128 + (((s >> 3) ^ (d & 7)) << 3) + (s & 7)] = p2[j];
      if (tid < 32) {
        s = c3 >> 3; d = ((c3 & 7) << 3) + j;
        sVt[d * 128 + (((s >> 3) ^ (d & 7)) << 3) + (s & 7)] = p3[j];
      }
    }
  }
  __syncthreads();

  // ---- per-wave independent q-tile loop (no further barriers) ----
  for (int qt = wave; qt < 7; qt += 4) {
    // Q fragments (B-operand): rows = q (clamped), two d-chunks
    int qrow = qt * 16 + l16; if (qrow > 99) qrow = 99;
    const u16* qp = Q + qbase + (size_t)qrow * EMB;
    short8 bq0 = *(const short8*)(qp + quad * 8);
    short8 bq1 = *(const short8*)(qp + 32 + quad * 8);

    // swapped QK^T: S^T tiles over kt
    f32x4 sacc[7];
#pragma unroll
    for (int kt = 0; kt < 7; ++kt) sacc[kt] = (f32x4){0.f, 0.f, 0.f, 0.f};
#pragma unroll
    for (int kt = 0; kt < 7; ++kt) {
      int krow = kt * 16 + l16; if (krow > 99) krow = 99;
      const u16* kp = Kb + qbase + (size_t)krow * EMB;
      short8 ak0 = *(const short8*)(kp + quad * 8);
      short8 ak1 = *(const short8*)(kp + 32 + quad * 8);
      sacc[kt] = MFMA16(ak0, bq0, sacc[kt]);
      sacc[kt] = MFMA16(ak1, bq1, sacc[kt]);
    }

    // register softmax over k (this lane's q = qt*16 + l16)
    float s[7][4];
    float mx = -1e30f;
#pragma unroll
    for (int kt = 0; kt < 7; ++kt)
#pragma unroll
      for (int r = 0; r < 4; ++r) {
        int k = kt * 16 + quad * 4 + r;
        float v = sacc[kt][r] * 0.125f;
        s[kt][r] = (k < S_LEN) ? v : -1e30f;
        mx = fmaxf(mx, s[kt][r]);
      }
    mx = fmaxf(mx, __shfl_xor(mx, 16));
    mx = fmaxf(mx, __shfl_xor(mx, 32));
    float sum = 0.f;
#pragma unroll
    for (int kt = 0; kt < 7; ++kt)
#pragma unroll
      for (int r = 0; r < 4; ++r) {
        int k = kt * 16 + quad * 4 + r;
        float e = (k < S_LEN) ? __expf(s[kt][r] - mx) : 0.f;
        s[kt][r] = e;
        sum += e;
      }
    sum += __shfl_xor(sum, 16);
    sum += __shfl_xor(sum, 32);
    float inv = 1.f / sum;

    // normalize; write attn_out straight from regs (aligned 16B, nt)
    int q = qt * 16 + l16;
    float* ao = attn_out + (size_t)bh * (S_LEN * S_LEN) + (size_t)q * S_LEN;
#pragma unroll
    for (int kt = 0; kt < 7; ++kt) {
#pragma unroll
      for (int r = 0; r < 4; ++r) s[kt][r] *= inv;
      int k0 = kt * 16 + quad * 4;
      if (q < S_LEN && k0 < S_LEN) {
        f32x4 v4 = {s[kt][0], s[kt][1], s[kt][2], s[kt][3]};
        __builtin_nontemporal_store(v4, (f32x4*)(ao + k0));
      }
    }

    // pack P -> bf16 pairs (lane holds k = kt*16 + quad*4 + r)
    unsigned pk[7][2];
#pragma unroll
    for (int kt = 0; kt < 7; ++kt) {
      asm("v_cvt_pk_bf16_f32 %0, %1, %2" : "=v"(pk[kt][0]) : "v"(s[kt][0]), "v"(s[kt][1]));
      asm("v_cvt_pk_bf16_f32 %0, %1, %2" : "=v"(pk[kt][1]) : "v"(s[kt][2]), "v"(s[kt][3]));
    }

    // PV: A-frag regroup via shfl, B from sVt, acc 4 d-tiles
    f32x4 oacc[4] = {};
    const int srcBase = l16 + ((quad & 1) << 5);   // lane of quad' = 2*(quad&1)
    const bool hiSel = (quad >> 1) != 0;
#pragma unroll
    for (int j = 0; j < 4; ++j) {                  // k = 32j .. 32j+31
      unsigned a[4];
#pragma unroll
      for (int sI = 0; sI < 4; ++sI) {
        int src = srcBase + ((sI >> 1) << 4);
        unsigned lo = (unsigned)__shfl((int)pk[2 * j][sI & 1], src);
        unsigned hi = (2 * j + 1 < 7) ? (unsigned)__shfl((int)pk[2 * j + 1][sI & 1], src) : 0u;
        a[sI] = hiSel ? hi : lo;
      }
      union { unsigned u[4]; short8 v8; } cu;
      cu.u[0] = a[0]; cu.u[1] = a[1]; cu.u[2] = a[2]; cu.u[3] = a[3];
      short8 af = cu.v8;
#pragma unroll
      for (int ni = 0; ni < 4; ++ni) {
        int rv = ni * 16 + l16;
        int cix = 4 * j + quad;
        short8 bv = *(const short8*)(sVt + rv * 128 + ((cix ^ (rv & 7)) << 3));
        oacc[ni] = MFMA16(af, bv, oacc[ni]);
      }
    }

    // attended write: row = qt*16 + quad*4 + r, col d = ni*16 + l16
#pragma unroll
    for (int ni = 0; ni < 4; ++ni) {
      int d = ni * 16 + l16;
#pragma unroll
      for (int r = 0; r < 4; ++r) {
        int row = qt * 16 + quad * 4 + r;
        if (row < S_LEN)
          attended[((size_t)b * S_LEN + row) * EMB + h * HDIM + d] = f2bf(oacc[ni][r]);
      }
    }
  }
}

// ---------------------------------------------------------------------------
extern "C" void kernel_launch(void* const* d_in, const int* in_sizes, int n_in,
                              void* d_out, int out_size, void* d_ws, size_t ws_size,
                              hipStream_t stream) {
  const float* x   = (const float*)d_in[0];
  const float* Wq  = (const float*)d_in[1];
  const float* bq  = (const float*)d_in[2];
  const float* Wk  = (const float*)d_in[3];
  const float* bk  = (const float*)d_in[4];
  const float* Wv  = (const float*)d_in[5];
  const float* bv  = (const float*)d_in[6];
  const float* Wo  = (const float*)d_in[7];
  const float* bo  = (const float*)d_in[8];
  const float* pos = (const float*)d_in[9];

  float* out  = (float*)d_out;                     // [B][E][S] f32
  float* attn = out + (size_t)BATCH * EMB * S_LEN; // [B][H][S][S] f32

  const size_t MTOT = (size_t)BATCH * S_LEN;       // 25600
  u16* ws   = (u16*)d_ws;
  u16* xT   = ws;                                  // [25600][1024] bf16
  u16* Qb   = ws + MTOT * EMB;
  u16* Kbuf = ws + 2 * MTOT * EMB;
  u16* Vb   = ws + 3 * MTOT * EMB;
  u16* WtQ  = ws + 4 * MTOT * EMB;
  u16* WtK  = WtQ + (size_t)EMB * EMB;
  u16* WtV  = WtK + (size_t)EMB * EMB;
  u16* WtO  = WtV + (size_t)EMB * EMB;
  u16* attended = xT;                              // reuse (xT dead after QKV gemm)
  u16* tmp      = Qb;                              // reuse (Q dead after attention)

  w_xpose<<<dim3(16, 16, 4), 256, 0, stream>>>(Wq, Wk, Wv, Wo, WtQ, WtK, WtV, WtO);
  xpose_pos<<<dim3(16, BATCH), 256, 0, stream>>>(x, pos, xT);
  gemm256<<<dim3(100, 4, 3), 512, 0, stream>>>(xT, WtQ, WtK, WtV, bq, bk, bv,
                                               Qb, Kbuf, Vb);
  attn_kernel<<<dim3(BATCH * NHEAD), 256, 0, stream>>>(Qb, Kbuf, Vb, attn, attended);
  gemm256<<<dim3(100, 4, 1), 512, 0, stream>>>(attended, WtO, WtO, WtO, bo, bo, bo,
                                               tmp, tmp, tmp);
  out_xpose<<<dim3(16, BATCH), 256, 0, stream>>>(tmp, out);
}